// Round 9
// baseline (160.305 us; speedup 1.0000x reference)
//
#include <hip/hip_runtime.h>
#include <hip/hip_bf16.h>

#define NUM_HEADS 16
#define HEAD_DIM  64
#define HIDDEN    1024
#define BATCH     2
#define SEQ       2048
#define K_DIM     1024
#define INV_NORM  0.125f
#define LOG2E     1.4426950408889634f
#define IN2       (INV_NORM * LOG2E)

typedef __attribute__((ext_vector_type(4)))  float f32x4;
typedef __attribute__((ext_vector_type(16))) float f32x16;
typedef __attribute__((ext_vector_type(8)))  short bf16x8;
typedef __attribute__((ext_vector_type(4)))  unsigned int u32x4;
typedef unsigned short u16;

__device__ inline u16 f2bf(float f) {
    __hip_bfloat16 h = __float2bfloat16(f);
    return __builtin_bit_cast(u16, h);
}
__device__ inline float bf2f(u16 u) {
    unsigned int v = ((unsigned int)u) << 16;
    return __builtin_bit_cast(float, v);
}
__device__ inline float fexp2(float x) { return __builtin_exp2f(x); }

__device__ inline f32x16 mfma32(bf16x8 a, bf16x8 b, f32x16 c) {
    return __builtin_amdgcn_mfma_f32_32x32x16_bf16(a, b, c, 0, 0, 0);
}

// async global->LDS, 16B per lane; LDS dest is wave-uniform base + lane*16
__device__ inline void gl_lds16(const u16* g, u16* s) {
    __builtin_amdgcn_global_load_lds(
        (const __attribute__((address_space(1))) unsigned int*)g,
        (__attribute__((address_space(3))) unsigned int*)s, 16, 0, 0);
}

// ---------------- fused fp32 -> bf16 conversion (x, W_qkv, W_dense) ----------------
__global__ __launch_bounds__(256) void cvt_all(
        const float* __restrict__ x, const float* __restrict__ wq,
        const float* __restrict__ wd,
        u16* __restrict__ xb, u16* __restrict__ wqb, u16* __restrict__ wdb) {
    int i = (blockIdx.x * 256 + threadIdx.x) * 4;   // 8388608 elements total
    const float* s; u16* d; int off;
    if (i < 4194304)      { s = x;  d = xb;  off = i; }
    else if (i < 7340032) { s = wq; d = wqb; off = i - 4194304; }
    else                  { s = wd; d = wdb; off = i - 7340032; }
    const float4 v = *reinterpret_cast<const float4*>(s + off);
    ushort4 o;
    o.x = f2bf(v.x); o.y = f2bf(v.y); o.z = f2bf(v.z); o.w = f2bf(v.w);
    *reinterpret_cast<ushort4*>(d + off) = o;
}

// ============ LDS-staged GEMM core: 128x128 tile, BK=64, single-buffer (m97 2-barrier) ============
#define GEMM_CORE(A_, B_)                                                              \
    const int tid = threadIdx.x;                                                       \
    const int w = tid >> 6, l = tid & 63;                                              \
    const int la = l & 31, hi = l >> 5;                                                \
    const int wr = w >> 1, wc = w & 1;                                                 \
    const int kperm = (((l & 7) ^ (l >> 3)) << 3);                                     \
    const u16* gA = A_ + (size_t)(mblk + w * 32 + (l >> 3)) * K_DIM + kperm;           \
    const u16* gB = B_ + (size_t)(nblk + w * 32 + (l >> 3)) * K_DIM + kperm;           \
    const int sca = (la & 7) << 3;                                                     \
    f32x16 acc[2][2] = {};                                                             \
    for (int kt = 0; kt < 16; ++kt) {                                                  \
        const int ko = kt * 64;                                                        \
        _Pragma("unroll")                                                              \
        for (int i = 0; i < 4; ++i) {                                                  \
            gl_lds16(gA + i * 8 * K_DIM + ko, &As[(w * 32 + i * 8) * 64]);             \
            gl_lds16(gB + i * 8 * K_DIM + ko, &Bs[(w * 32 + i * 8) * 64]);             \
        }                                                                              \
        asm volatile("s_waitcnt vmcnt(0)" ::: "memory");                               \
        __syncthreads();                                                               \
        const u16* pA = &As[(wr * 64 + la) * 64];                                      \
        const u16* pB = &Bs[(wc * 64 + la) * 64];                                      \
        _Pragma("unroll")                                                              \
        for (int kk = 0; kk < 4; ++kk) {                                               \
            const int co = (kk * 16 + hi * 8) ^ sca;                                   \
            bf16x8 a0 = *reinterpret_cast<const bf16x8*>(pA + co);                     \
            bf16x8 a1 = *reinterpret_cast<const bf16x8*>(pA + 32 * 64 + co);           \
            bf16x8 b0 = *reinterpret_cast<const bf16x8*>(pB + co);                     \
            bf16x8 b1 = *reinterpret_cast<const bf16x8*>(pB + 32 * 64 + co);           \
            acc[0][0] = mfma32(a0, b0, acc[0][0]);                                     \
            acc[0][1] = mfma32(a0, b1, acc[0][1]);                                     \
            acc[1][0] = mfma32(a1, b0, acc[1][0]);                                     \
            acc[1][1] = mfma32(a1, b1, acc[1][1]);                                     \
        }                                                                              \
        __syncthreads();                                                               \
    }

// ---------------- QKV GEMM + scatter to q/k/vT ----------------
__global__ __launch_bounds__(256) void gemm_qkv(
        const u16* __restrict__ A, const u16* __restrict__ W,
        const float* __restrict__ bias,
        u16* __restrict__ qo, u16* __restrict__ ko2, u16* __restrict__ vTo) {
    __shared__ u16 As[128 * 64];
    __shared__ u16 Bs[128 * 64];
    int lin = blockIdx.x;
    int sw = (lin & 7) * 96 + (lin >> 3);
    const int mblk = (sw & 31) * 128;
    const int nblk = (sw >> 5) * 128;
    GEMM_CORE(A, W)
    #pragma unroll
    for (int mi = 0; mi < 2; ++mi)
    #pragma unroll
    for (int ni = 0; ni < 2; ++ni) {
        int c = nblk + wc * 64 + ni * 32 + la;   // fused col: h*192 + which*64 + d
        int h = c / 192, rem = c - h * 192;
        int which = rem >> 6, d = rem & 63;
        float bv = bias[c];
        #pragma unroll
        for (int r = 0; r < 16; ++r) {
            int m = mblk + wr * 64 + mi * 32 + (r & 3) + 8 * (r >> 2) + 4 * hi;
            int bb = m >> 11, s = m & (SEQ - 1);
            int bh = bb * NUM_HEADS + h;
            u16 o = f2bf(acc[mi][ni][r] + bv);
            if (which == 0)      qo[((size_t)bh * SEQ + s) * HEAD_DIM + d] = o;
            else if (which == 1) ko2[((size_t)bh * SEQ + s) * HEAD_DIM + d] = o;
            else                 vTo[((size_t)bh * HEAD_DIM + d) * SEQ + s] = o;
        }
    }
}

// ---------------- Dense GEMM + bias + residual ----------------
__global__ __launch_bounds__(256) void gemm_dense(
        const u16* __restrict__ A, const u16* __restrict__ W,
        const float* __restrict__ bias, const float* __restrict__ residual,
        float* __restrict__ out) {
    __shared__ u16 As[128 * 64];
    __shared__ u16 Bs[128 * 64];
    int lin = blockIdx.x;
    int sw = (lin & 7) * 32 + (lin >> 3);
    const int mblk = (sw & 31) * 128;
    const int nblk = (sw >> 5) * 128;
    GEMM_CORE(A, W)
    #pragma unroll
    for (int mi = 0; mi < 2; ++mi)
    #pragma unroll
    for (int ni = 0; ni < 2; ++ni) {
        int c = nblk + wc * 64 + ni * 32 + la;
        float bv = bias[c];
        #pragma unroll
        for (int r = 0; r < 16; ++r) {
            int m = mblk + wr * 64 + mi * 32 + (r & 3) + 8 * (r >> 2) + 4 * hi;
            out[(size_t)m * HIDDEN + c] = acc[mi][ni][r] + bv + residual[(size_t)m * HIDDEN + c];
        }
    }
}

// ---------------- per-bh max ||k||, and reset attn work counters ----------------
__global__ __launch_bounds__(256) void knorm_max(const u16* __restrict__ K,
                                                 float* __restrict__ kn,
                                                 unsigned int* __restrict__ ctr) {
    if (blockIdx.x == 0 && threadIdx.x < 8) ctr[threadIdx.x] = 0;  // stream-ordered
    __shared__ float red[256];
    const int bh = blockIdx.x;
    const u16* kp = K + (size_t)bh * SEQ * HEAD_DIM;
    float mx = 0.f;
    for (int s = threadIdx.x; s < SEQ; s += 256) {
        const bf16x8* row = reinterpret_cast<const bf16x8*>(kp + (size_t)s * HEAD_DIM);
        float ss = 0.f;
        #pragma unroll
        for (int j = 0; j < 8; ++j) {
            bf16x8 v = row[j];
            #pragma unroll
            for (int e = 0; e < 8; ++e) {
                float f = bf2f((u16)v[e]);
                ss = fmaf(f, f, ss);
            }
        }
        mx = fmaxf(mx, ss);
    }
    red[threadIdx.x] = mx;
    __syncthreads();
    for (int off = 128; off; off >>= 1) {
        if (threadIdx.x < (unsigned)off)
            red[threadIdx.x] = fmaxf(red[threadIdx.x], red[threadIdx.x + off]);
        __syncthreads();
    }
    if (threadIdx.x == 0) kn[bh] = sqrtf(red[0]);
}

// ---------------- Flash attention: group-partitioned work-stealing + split-K ----------------
// Group g = blockIdx.x & 7 (~XCD under round-robin; perf-only) owns 4 bh:
// h in {g, 15-g} x b in {0,1}. Steep+shallow head pairing balances group work.
// Item (within group) = (sub, qt): 256 items, heavy qt first.
__global__ __launch_bounds__(256) void attn(
        const u16* __restrict__ Q, const u16* __restrict__ Kb,
        const u16* __restrict__ VT, const float* __restrict__ alibi,
        const float* __restrict__ kn, u16* __restrict__ ctx,
        unsigned int* __restrict__ ctr) {
    __shared__ float o_l[4][64][33];
    __shared__ float ml[4][2][32];
    __shared__ unsigned int s_idx;
    const int grp  = blockIdx.x & 7;
    const int wave = threadIdx.x >> 6;
    const int lane = threadIdx.x & 63;
    const int la = lane & 31, hi = lane >> 5;

    for (;;) {
        if (threadIdx.x == 0) s_idx = atomicAdd(ctr + grp, 1u);
        __syncthreads();                     // publish s_idx; protect o_l reuse
        const unsigned int idx = s_idx;
        if (idx >= 256) return;
        const int sub = idx & 3;
        const int qt  = 63 - (int)(idx >> 2);    // heavy q-tiles first
        const int h   = (sub & 1) ? (15 - grp) : grp;
        const int bh  = (sub >> 1) * 16 + h;
        const int qw  = qt * 32;
        const size_t sb = (size_t)bh * SEQ;
        const float slope2 = alibi[sb + 1] * LOG2E;

        const u16* qp = Q + (sb + qw + la) * HEAD_DIM + hi * 8;
        bf16x8 qf0 = *reinterpret_cast<const bf16x8*>(qp);
        bf16x8 qf1 = *reinterpret_cast<const bf16x8*>(qp + 16);
        bf16x8 qf2 = *reinterpret_cast<const bf16x8*>(qp + 32);
        bf16x8 qf3 = *reinterpret_cast<const bf16x8*>(qp + 48);

        f32x16 o0 = {}, o1 = {};
        float m_i = -INFINITY, l_i = 0.f;

        int t = qt - wave;
        if (t >= 0) {
            float qss = 0.f;
            #pragma unroll
            for (int e = 0; e < 8; ++e) {
                float f;
                f = bf2f((u16)qf0[e]); qss = fmaf(f, f, qss);
                f = bf2f((u16)qf1[e]); qss = fmaf(f, f, qss);
                f = bf2f((u16)qf2[e]); qss = fmaf(f, f, qss);
                f = bf2f((u16)qf3[e]); qss = fmaf(f, f, qss);
            }
            qss += __shfl_xor(qss, 32);
            float qmx = qss;
            #pragma unroll
            for (int off = 1; off <= 16; off <<= 1) qmx = fmaxf(qmx, __shfl_xor(qmx, off));
            const float kb = sqrtf(qmx) * kn[bh] * IN2;

            float skr2[16];
            #pragma unroll
            for (int r = 0; r < 16; ++r)
                skr2[r] = slope2 * (float)((r & 3) + 8 * (r >> 2) + 4 * hi);

            // prologue: load tile t
            const u16* kp = Kb + (sb + t * 32 + la) * HEAD_DIM + hi * 8;
            bf16x8 kc0 = *reinterpret_cast<const bf16x8*>(kp);
            bf16x8 kc1 = *reinterpret_cast<const bf16x8*>(kp + 16);
            bf16x8 kc2 = *reinterpret_cast<const bf16x8*>(kp + 32);
            bf16x8 kc3 = *reinterpret_cast<const bf16x8*>(kp + 48);
            const u16* vp = VT + ((size_t)bh * HEAD_DIM + la) * SEQ + t * 32 + hi * 8;
            bf16x8 vc00 = *reinterpret_cast<const bf16x8*>(vp);
            bf16x8 vc01 = *reinterpret_cast<const bf16x8*>(vp + 16);
            bf16x8 vc10 = *reinterpret_cast<const bf16x8*>(vp + 32 * SEQ);
            bf16x8 vc11 = *reinterpret_cast<const bf16x8*>(vp + 32 * SEQ + 16);

            for (;;) {
                const int k0 = t * 32;
                f32x16 sca = {}, scb = {};
                sca = mfma32(kc0, qf0, sca);
                scb = mfma32(kc1, qf1, scb);
                sca = mfma32(kc2, qf2, sca);
                scb = mfma32(kc3, qf3, scb);

                float s[16];
                const float base2 = slope2 * (float)k0;
                #pragma unroll
                for (int r = 0; r < 16; ++r)
                    s[r] = fmaf(sca[r] + scb[r], IN2, base2 + skr2[r]);
                if (t == qt) {   // diagonal tile (wave 0 only)
                    #pragma unroll
                    for (int r = 0; r < 16; ++r) {
                        int kr = (r & 3) + 8 * (r >> 2) + 4 * hi;
                        if (kr > la) s[r] = -INFINITY;
                    }
                }
                float ma = fmaxf(fmaxf(s[0], s[1]), fmaxf(s[2], s[3]));
                float mb = fmaxf(fmaxf(s[4], s[5]), fmaxf(s[6], s[7]));
                float mc = fmaxf(fmaxf(s[8], s[9]), fmaxf(s[10], s[11]));
                float md = fmaxf(fmaxf(s[12], s[13]), fmaxf(s[14], s[15]));
                float mx = fmaxf(fmaxf(ma, mb), fmaxf(mc, md));
                mx = fmaxf(mx, __shfl_xor(mx, 32));
                if (!__all(mx <= m_i + 11.54f)) {   // defer-max (T13)
                    float mnew = fmaxf(m_i, mx);
                    float scl = fexp2(m_i - mnew);
                    l_i *= scl;
                    #pragma unroll
                    for (int r = 0; r < 16; ++r) { o0[r] *= scl; o1[r] *= scl; }
                    m_i = mnew;
                }

                // continue decision (same m_i as before) BEFORE prefetch: no wasted loads
                const int tn = t - 4;
                const bool cont =
                    (tn >= 0) && !__all(kb + slope2 * (float)(tn * 32 + 31) < m_i - 36.f);
                bf16x8 kn0, kn1, kn2, kn3, vn00, vn01, vn10, vn11;
                if (cont) {   // wave-uniform; K/V(t-4) latency hides under exp2+pack+PV
                    const u16* kpn = Kb + (sb + tn * 32 + la) * HEAD_DIM + hi * 8;
                    kn0 = *reinterpret_cast<const bf16x8*>(kpn);
                    kn1 = *reinterpret_cast<const bf16x8*>(kpn + 16);
                    kn2 = *reinterpret_cast<const bf16x8*>(kpn + 32);
                    kn3 = *reinterpret_cast<const bf16x8*>(kpn + 48);
                    const u16* vpn = VT + ((size_t)bh * HEAD_DIM + la) * SEQ + tn * 32 + hi * 8;
                    vn00 = *reinterpret_cast<const bf16x8*>(vpn);
                    vn01 = *reinterpret_cast<const bf16x8*>(vpn + 16);
                    vn10 = *reinterpret_cast<const bf16x8*>(vpn + 32 * SEQ);
                    vn11 = *reinterpret_cast<const bf16x8*>(vpn + 32 * SEQ + 16);
                }

                #pragma unroll
                for (int r = 0; r < 16; ++r) s[r] = fexp2(s[r] - m_i);
                float sa = (s[0] + s[1]) + (s[2] + s[3]);
                float sbs = (s[4] + s[5]) + (s[6] + s[7]);
                float scs = (s[8] + s[9]) + (s[10] + s[11]);
                float sd = (s[12] + s[13]) + (s[14] + s[15]);
                float rs = (sa + sbs) + (scs + sd);
                rs += __shfl_xor(rs, 32);
                l_i += rs;

                unsigned int pk[8], swp[8];
                #pragma unroll
                for (int m = 0; m < 4; ++m) {
                    pk[2 * m]     = (unsigned)f2bf(s[4 * m])     | ((unsigned)f2bf(s[4 * m + 1]) << 16);
                    pk[2 * m + 1] = (unsigned)f2bf(s[4 * m + 2]) | ((unsigned)f2bf(s[4 * m + 3]) << 16);
                }
                #pragma unroll
                for (int i = 0; i < 8; ++i) swp[i] = __shfl_xor(pk[i], 32);
                u32x4 pb0, pb1;
                pb0[0] = hi ? swp[2] : pk[0];  pb0[1] = hi ? swp[3] : pk[1];
                pb0[2] = hi ? pk[2]  : swp[0]; pb0[3] = hi ? pk[3]  : swp[1];
                pb1[0] = hi ? swp[6] : pk[4];  pb1[1] = hi ? swp[7] : pk[5];
                pb1[2] = hi ? pk[6]  : swp[4]; pb1[3] = hi ? pk[7]  : swp[5];
                bf16x8 pf0 = __builtin_bit_cast(bf16x8, pb0);
                bf16x8 pf1 = __builtin_bit_cast(bf16x8, pb1);

                o0 = mfma32(vc00, pf0, o0);
                o0 = mfma32(vc01, pf1, o0);
                o1 = mfma32(vc10, pf0, o1);
                o1 = mfma32(vc11, pf1, o1);

                if (!cont) break;
                kc0 = kn0; kc1 = kn1; kc2 = kn2; kc3 = kn3;
                vc00 = vn00; vc01 = vn01; vc10 = vn10; vc11 = vn11;
                t = tn;
            }
        }

        // ---- write partials to LDS ----
        if (hi == 0) { ml[wave][0][la] = m_i; ml[wave][1][la] = l_i; }
        #pragma unroll
        for (int r = 0; r < 16; ++r) {
            int d = (r & 3) + 8 * (r >> 2) + 4 * hi;
            o_l[wave][d][la]      = o0[r];
            o_l[wave][d + 32][la] = o1[r];
        }
        __syncthreads();

        // ---- combine: thread = (q, 8-wide d slab) ----
        const int q  = threadIdx.x >> 3;
        const int d0 = (threadIdx.x & 7) * 8;
        float m0w = ml[0][0][q], m1w = ml[1][0][q], m2w = ml[2][0][q], m3w = ml[3][0][q];
        float M = fmaxf(fmaxf(m0w, m1w), fmaxf(m2w, m3w));
        float s0 = fexp2(m0w - M), s1 = fexp2(m1w - M);
        float s2 = fexp2(m2w - M), s3 = fexp2(m3w - M);
        float L = s0 * ml[0][1][q] + s1 * ml[1][1][q] + s2 * ml[2][1][q] + s3 * ml[3][1][q];
        float inv = 1.0f / L;
        unsigned int packed[4];
        #pragma unroll
        for (int e2 = 0; e2 < 4; ++e2) {
            float Oa = s0 * o_l[0][d0 + 2 * e2][q] + s1 * o_l[1][d0 + 2 * e2][q]
                     + s2 * o_l[2][d0 + 2 * e2][q] + s3 * o_l[3][d0 + 2 * e2][q];
            float Ob = s0 * o_l[0][d0 + 2 * e2 + 1][q] + s1 * o_l[1][d0 + 2 * e2 + 1][q]
                     + s2 * o_l[2][d0 + 2 * e2 + 1][q] + s3 * o_l[3][d0 + 2 * e2 + 1][q];
            packed[e2] = (unsigned)f2bf(Oa * inv) | ((unsigned)f2bf(Ob * inv) << 16);
        }
        const int b = bh >> 4, hh = bh & 15;
        u32x4 pv; pv[0] = packed[0]; pv[1] = packed[1]; pv[2] = packed[2]; pv[3] = packed[3];
        *reinterpret_cast<u32x4*>(
            &ctx[((size_t)(b * SEQ + qw + q)) * HIDDEN + hh * HEAD_DIM + d0]) = pv;
    }
}

extern "C" void kernel_launch(void* const* d_in, const int* in_sizes, int n_in,
                              void* d_out, int out_size, void* d_ws, size_t ws_size,
                              hipStream_t stream) {
    const float* x        = (const float*)d_in[0];
    const float* residual = (const float*)d_in[1];
    const float* alibi    = (const float*)d_in[2];
    const float* W_qkv    = (const float*)d_in[4];
    const float* b_qkv    = (const float*)d_in[5];
    const float* W_dense  = (const float*)d_in[6];
    const float* b_dense  = (const float*)d_in[7];
    float* out = (float*)d_out;

    char* ws = (char*)d_ws;
    u16* xb  = (u16*)(ws);                 //  8 MB  x bf16
    u16* wqb = (u16*)(ws + 8388608);       //  6 MB  W_qkv bf16
    u16* wdb = (u16*)(ws + 14680064);      //  2 MB  W_dense bf16
    u16* q   = (u16*)(ws + 16777216);      //  8 MB  [B][H][S][64]
    u16* k   = (u16*)(ws + 25165824);      //  8 MB  [B][H][S][64]
    u16* vT  = (u16*)(ws + 33554432);      //  8 MB  [B][H][64][S]
    u16* ctx = (u16*)(ws + 41943040);      //  8 MB  [B*S][1024]
    float* kn = (float*)(ws + 50331648);   //  128 B per-bh max ||k||
    unsigned int* ctr = (unsigned int*)(ws + 50331648 + 256);  // 8 group counters

    cvt_all<<<8192, 256, 0, stream>>>(x, W_qkv, W_dense, xb, wqb, wdb);
    gemm_qkv<<<768, 256, 0, stream>>>(xb, wqb, b_qkv, q, k, vT);
    knorm_max<<<32, 256, 0, stream>>>(k, kn, ctr);
    attn<<<1024, 256, 0, stream>>>(q, k, vT, alibi, kn, ctx, ctr);
    gemm_dense<<<256, 256, 0, stream>>>(ctx, wdb, b_dense, residual, out);
}

// Round 10
// 156.000 us; speedup vs baseline: 1.0276x; 1.0276x over previous
//
#include <hip/hip_runtime.h>
#include <hip/hip_bf16.h>

#define NUM_HEADS 16
#define HEAD_DIM  64
#define HIDDEN    1024
#define BATCH     2
#define SEQ       2048
#define K_DIM     1024
#define INV_NORM  0.125f
#define LOG2E     1.4426950408889634f
#define IN2       (INV_NORM * LOG2E)
#define N_ITEMS   2048

typedef __attribute__((ext_vector_type(4)))  float f32x4;
typedef __attribute__((ext_vector_type(16))) float f32x16;
typedef __attribute__((ext_vector_type(8)))  short bf16x8;
typedef __attribute__((ext_vector_type(4)))  unsigned int u32x4;
typedef unsigned short u16;

__device__ inline u16 f2bf(float f) {
    __hip_bfloat16 h = __float2bfloat16(f);
    return __builtin_bit_cast(u16, h);
}
__device__ inline float bf2f(u16 u) {
    unsigned int v = ((unsigned int)u) << 16;
    return __builtin_bit_cast(float, v);
}
__device__ inline float fexp2(float x) { return __builtin_exp2f(x); }

__device__ inline f32x16 mfma32(bf16x8 a, bf16x8 b, f32x16 c) {
    return __builtin_amdgcn_mfma_f32_32x32x16_bf16(a, b, c, 0, 0, 0);
}

// async global->LDS, 16B per lane; LDS dest is wave-uniform base + lane*16
__device__ inline void gl_lds16(const u16* g, u16* s) {
    __builtin_amdgcn_global_load_lds(
        (const __attribute__((address_space(1))) unsigned int*)g,
        (__attribute__((address_space(3))) unsigned int*)s, 16, 0, 0);
}

// ---------------- fused fp32 -> bf16 conversion (x, W_qkv, W_dense) ----------------
__global__ __launch_bounds__(256) void cvt_all(
        const float* __restrict__ x, const float* __restrict__ wq,
        const float* __restrict__ wd,
        u16* __restrict__ xb, u16* __restrict__ wqb, u16* __restrict__ wdb) {
    int i = (blockIdx.x * 256 + threadIdx.x) * 4;   // 8388608 elements total
    const float* s; u16* d; int off;
    if (i < 4194304)      { s = x;  d = xb;  off = i; }
    else if (i < 7340032) { s = wq; d = wqb; off = i - 4194304; }
    else                  { s = wd; d = wdb; off = i - 7340032; }
    const float4 v = *reinterpret_cast<const float4*>(s + off);
    ushort4 o;
    o.x = f2bf(v.x); o.y = f2bf(v.y); o.z = f2bf(v.z); o.w = f2bf(v.w);
    *reinterpret_cast<ushort4*>(d + off) = o;
}

// ============ LDS-staged GEMM core: 128x128 tile, BK=64, single-buffer (m97 2-barrier) ============
#define GEMM_CORE(A_, B_)                                                              \
    const int tid = threadIdx.x;                                                       \
    const int w = tid >> 6, l = tid & 63;                                              \
    const int la = l & 31, hi = l >> 5;                                                \
    const int wr = w >> 1, wc = w & 1;                                                 \
    const int kperm = (((l & 7) ^ (l >> 3)) << 3);                                     \
    const u16* gA = A_ + (size_t)(mblk + w * 32 + (l >> 3)) * K_DIM + kperm;           \
    const u16* gB = B_ + (size_t)(nblk + w * 32 + (l >> 3)) * K_DIM + kperm;           \
    const int sca = (la & 7) << 3;                                                     \
    f32x16 acc[2][2] = {};                                                             \
    for (int kt = 0; kt < 16; ++kt) {                                                  \
        const int ko = kt * 64;                                                        \
        _Pragma("unroll")                                                              \
        for (int i = 0; i < 4; ++i) {                                                  \
            gl_lds16(gA + i * 8 * K_DIM + ko, &As[(w * 32 + i * 8) * 64]);             \
            gl_lds16(gB + i * 8 * K_DIM + ko, &Bs[(w * 32 + i * 8) * 64]);             \
        }                                                                              \
        asm volatile("s_waitcnt vmcnt(0)" ::: "memory");                               \
        __syncthreads();                                                               \
        const u16* pA = &As[(wr * 64 + la) * 64];                                      \
        const u16* pB = &Bs[(wc * 64 + la) * 64];                                      \
        _Pragma("unroll")                                                              \
        for (int kk = 0; kk < 4; ++kk) {                                               \
            const int co = (kk * 16 + hi * 8) ^ sca;                                   \
            bf16x8 a0 = *reinterpret_cast<const bf16x8*>(pA + co);                     \
            bf16x8 a1 = *reinterpret_cast<const bf16x8*>(pA + 32 * 64 + co);           \
            bf16x8 b0 = *reinterpret_cast<const bf16x8*>(pB + co);                     \
            bf16x8 b1 = *reinterpret_cast<const bf16x8*>(pB + 32 * 64 + co);           \
            acc[0][0] = mfma32(a0, b0, acc[0][0]);                                     \
            acc[0][1] = mfma32(a0, b1, acc[0][1]);                                     \
            acc[1][0] = mfma32(a1, b0, acc[1][0]);                                     \
            acc[1][1] = mfma32(a1, b1, acc[1][1]);                                     \
        }                                                                              \
        __syncthreads();                                                               \
    }

// ---------------- QKV GEMM + scatter to q/k/vT ----------------
__global__ __launch_bounds__(256) void gemm_qkv(
        const u16* __restrict__ A, const u16* __restrict__ W,
        const float* __restrict__ bias,
        u16* __restrict__ qo, u16* __restrict__ ko2, u16* __restrict__ vTo) {
    __shared__ u16 As[128 * 64];
    __shared__ u16 Bs[128 * 64];
    int lin = blockIdx.x;
    int sw = (lin & 7) * 96 + (lin >> 3);
    const int mblk = (sw & 31) * 128;
    const int nblk = (sw >> 5) * 128;
    GEMM_CORE(A, W)
    #pragma unroll
    for (int mi = 0; mi < 2; ++mi)
    #pragma unroll
    for (int ni = 0; ni < 2; ++ni) {
        int c = nblk + wc * 64 + ni * 32 + la;   // fused col: h*192 + which*64 + d
        int h = c / 192, rem = c - h * 192;
        int which = rem >> 6, d = rem & 63;
        float bv = bias[c];
        #pragma unroll
        for (int r = 0; r < 16; ++r) {
            int m = mblk + wr * 64 + mi * 32 + (r & 3) + 8 * (r >> 2) + 4 * hi;
            int bb = m >> 11, s = m & (SEQ - 1);
            int bh = bb * NUM_HEADS + h;
            u16 o = f2bf(acc[mi][ni][r] + bv);
            if (which == 0)      qo[((size_t)bh * SEQ + s) * HEAD_DIM + d] = o;
            else if (which == 1) ko2[((size_t)bh * SEQ + s) * HEAD_DIM + d] = o;
            else                 vTo[((size_t)bh * HEAD_DIM + d) * SEQ + s] = o;
        }
    }
}

// ---------------- Dense GEMM + bias + residual ----------------
__global__ __launch_bounds__(256) void gemm_dense(
        const u16* __restrict__ A, const u16* __restrict__ W,
        const float* __restrict__ bias, const float* __restrict__ residual,
        float* __restrict__ out) {
    __shared__ u16 As[128 * 64];
    __shared__ u16 Bs[128 * 64];
    int lin = blockIdx.x;
    int sw = (lin & 7) * 32 + (lin >> 3);
    const int mblk = (sw & 31) * 128;
    const int nblk = (sw >> 5) * 128;
    GEMM_CORE(A, W)
    #pragma unroll
    for (int mi = 0; mi < 2; ++mi)
    #pragma unroll
    for (int ni = 0; ni < 2; ++ni) {
        int c = nblk + wc * 64 + ni * 32 + la;
        float bv = bias[c];
        #pragma unroll
        for (int r = 0; r < 16; ++r) {
            int m = mblk + wr * 64 + mi * 32 + (r & 3) + 8 * (r >> 2) + 4 * hi;
            out[(size_t)m * HIDDEN + c] = acc[mi][ni][r] + bv + residual[(size_t)m * HIDDEN + c];
        }
    }
}

// ---------------- per-bh max ||k||, and reset attn work counter ----------------
__global__ __launch_bounds__(256) void knorm_max(const u16* __restrict__ K,
                                                 float* __restrict__ kn,
                                                 unsigned int* __restrict__ ctr) {
    if (blockIdx.x == 0 && threadIdx.x == 0) *ctr = 0;   // stream-ordered before attn
    __shared__ float red[256];
    const int bh = blockIdx.x;
    const u16* kp = K + (size_t)bh * SEQ * HEAD_DIM;
    float mx = 0.f;
    for (int s = threadIdx.x; s < SEQ; s += 256) {
        const bf16x8* row = reinterpret_cast<const bf16x8*>(kp + (size_t)s * HEAD_DIM);
        float ss = 0.f;
        #pragma unroll
        for (int j = 0; j < 8; ++j) {
            bf16x8 v = row[j];
            #pragma unroll
            for (int e = 0; e < 8; ++e) {
                float f = bf2f((u16)v[e]);
                ss = fmaf(f, f, ss);
            }
        }
        mx = fmaxf(mx, ss);
    }
    red[threadIdx.x] = mx;
    __syncthreads();
    for (int off = 128; off; off >>= 1) {
        if (threadIdx.x < (unsigned)off)
            red[threadIdx.x] = fmaxf(red[threadIdx.x], red[threadIdx.x + off]);
        __syncthreads();
    }
    if (threadIdx.x == 0) kn[bh] = sqrtf(red[0]);
}

// ---------------- Flash attention: static-max softmax + global work-stealing ----------------
// M_row = kb + slope2*row is a STATIC upper bound on every score of the row
// (kb = max|q||k|*INV_NORM*log2e per wave; identical across the block's 4 waves).
// P = exp2(s - M_row): no max-reduce, no rescale, no m/l state; partials combine
// by PLAIN SUMS. Tail skip is a static loop bound t_lo (tail/L < 2^-36).
__global__ __launch_bounds__(256, 4) void attn(
        const u16* __restrict__ Q, const u16* __restrict__ Kb,
        const u16* __restrict__ VT, const float* __restrict__ alibi,
        const float* __restrict__ kn, u16* __restrict__ ctx,
        unsigned int* __restrict__ ctr) {
    __shared__ float o_l[4][64][33];
    __shared__ float ml[4][32];
    __shared__ unsigned int s_idx;
    const int wave = threadIdx.x >> 6;
    const int lane = threadIdx.x & 63;
    const int la = lane & 31, hi = lane >> 5;

    for (;;) {
        if (threadIdx.x == 0) s_idx = atomicAdd(ctr, 1u);
        __syncthreads();                     // publish s_idx; protect o_l reuse
        const unsigned int idx = s_idx;
        if (idx >= N_ITEMS) return;
        const int bh = idx & 31;
        const int qt = 63 - (int)(idx >> 5); // heavy q-tiles first
        const int qw = qt * 32;
        const size_t sb = (size_t)bh * SEQ;
        const float slope2 = alibi[sb + 1] * LOG2E;

        const u16* qp = Q + (sb + qw + la) * HEAD_DIM + hi * 8;
        bf16x8 qf0 = *reinterpret_cast<const bf16x8*>(qp);
        bf16x8 qf1 = *reinterpret_cast<const bf16x8*>(qp + 16);
        bf16x8 qf2 = *reinterpret_cast<const bf16x8*>(qp + 32);
        bf16x8 qf3 = *reinterpret_cast<const bf16x8*>(qp + 48);

        // kb = sqrt(max_row ||q||^2) * max||k|| * INV_NORM * log2e
        float qss = 0.f;
        #pragma unroll
        for (int e = 0; e < 8; ++e) {
            float f;
            f = bf2f((u16)qf0[e]); qss = fmaf(f, f, qss);
            f = bf2f((u16)qf1[e]); qss = fmaf(f, f, qss);
            f = bf2f((u16)qf2[e]); qss = fmaf(f, f, qss);
            f = bf2f((u16)qf3[e]); qss = fmaf(f, f, qss);
        }
        qss += __shfl_xor(qss, 32);
        float qmx = qss;
        #pragma unroll
        for (int off = 1; off <= 16; off <<= 1) qmx = fmaxf(qmx, __shfl_xor(qmx, off));
        const float kb = sqrtf(qmx) * kn[bh] * IN2;

        // static window: keep tiles with slope2*(k0+31-qw) >= -(47 + 2kb)
        const float Wf = (47.f + 2.f * kb) / slope2;
        const int lo_k = qw - 31 - (int)Wf;
        const int t_lo = lo_k <= 0 ? 0 : ((lo_k + 31) >> 5);

        // per-lane softmax addend: cl[r] = slope2*(key_off - la) - kb
        float cl[16];
        #pragma unroll
        for (int r = 0; r < 16; ++r)
            cl[r] = slope2 * (float)((r & 3) + 8 * (r >> 2) + 4 * hi - la) - kb;

        f32x16 o0 = {}, o1 = {};
        float l_i = 0.f;

        for (int t = qt - wave; t >= t_lo; t -= 4) {
            const int k0 = t * 32;
            const u16* kp = Kb + (sb + k0 + la) * HEAD_DIM + hi * 8;
            bf16x8 kc0 = *reinterpret_cast<const bf16x8*>(kp);
            bf16x8 kc1 = *reinterpret_cast<const bf16x8*>(kp + 16);
            bf16x8 kc2 = *reinterpret_cast<const bf16x8*>(kp + 32);
            bf16x8 kc3 = *reinterpret_cast<const bf16x8*>(kp + 48);
            f32x16 sca = {}, scb = {};
            sca = mfma32(kc0, qf0, sca);
            scb = mfma32(kc1, qf1, scb);
            sca = mfma32(kc2, qf2, sca);
            scb = mfma32(kc3, qf3, scb);

            // V loads issued early: latency hides under exp2+pack
            const u16* vp = VT + ((size_t)bh * HEAD_DIM + la) * SEQ + k0 + hi * 8;
            bf16x8 vc00 = *reinterpret_cast<const bf16x8*>(vp);
            bf16x8 vc01 = *reinterpret_cast<const bf16x8*>(vp + 16);
            bf16x8 vc10 = *reinterpret_cast<const bf16x8*>(vp + 32 * SEQ);
            bf16x8 vc11 = *reinterpret_cast<const bf16x8*>(vp + 32 * SEQ + 16);

            const float Dt = slope2 * (float)(k0 - qw);
            float p[16];
            #pragma unroll
            for (int r = 0; r < 16; ++r)
                p[r] = fexp2(fmaf(sca[r] + scb[r], IN2, cl[r] + Dt));
            if (t == qt) {   // causal diagonal tile (wave 0 only)
                #pragma unroll
                for (int r = 0; r < 16; ++r) {
                    int kr = (r & 3) + 8 * (r >> 2) + 4 * hi;
                    if (kr > la) p[r] = 0.f;
                }
            }
            l_i += ((p[0] + p[1]) + (p[2] + p[3])) + ((p[4] + p[5]) + (p[6] + p[7]))
                 + ((p[8] + p[9]) + (p[10] + p[11])) + ((p[12] + p[13]) + (p[14] + p[15]));

            unsigned int pk[8], swp[8];
            #pragma unroll
            for (int m = 0; m < 4; ++m) {
                pk[2 * m]     = (unsigned)f2bf(p[4 * m])     | ((unsigned)f2bf(p[4 * m + 1]) << 16);
                pk[2 * m + 1] = (unsigned)f2bf(p[4 * m + 2]) | ((unsigned)f2bf(p[4 * m + 3]) << 16);
            }
            #pragma unroll
            for (int i = 0; i < 8; ++i) swp[i] = __shfl_xor(pk[i], 32);
            u32x4 pb0, pb1;
            pb0[0] = hi ? swp[2] : pk[0];  pb0[1] = hi ? swp[3] : pk[1];
            pb0[2] = hi ? pk[2]  : swp[0]; pb0[3] = hi ? pk[3]  : swp[1];
            pb1[0] = hi ? swp[6] : pk[4];  pb1[1] = hi ? swp[7] : pk[5];
            pb1[2] = hi ? pk[6]  : swp[4]; pb1[3] = hi ? pk[7]  : swp[5];
            bf16x8 pf0 = __builtin_bit_cast(bf16x8, pb0);
            bf16x8 pf1 = __builtin_bit_cast(bf16x8, pb1);

            o0 = mfma32(vc00, pf0, o0);
            o0 = mfma32(vc01, pf1, o0);
            o1 = mfma32(vc10, pf0, o1);
            o1 = mfma32(vc11, pf1, o1);
        }

        // ---- write partials (shared static M -> plain sums in combine) ----
        l_i += __shfl_xor(l_i, 32);
        if (hi == 0) ml[wave][la] = l_i;
        #pragma unroll
        for (int r = 0; r < 16; ++r) {
            int d = (r & 3) + 8 * (r >> 2) + 4 * hi;
            o_l[wave][d][la]      = o0[r];
            o_l[wave][d + 32][la] = o1[r];
        }
        __syncthreads();

        // ---- combine: thread = (q, 8-wide d slab); plain sums ----
        const int q  = threadIdx.x >> 3;
        const int d0 = (threadIdx.x & 7) * 8;
        float L = ml[0][q] + ml[1][q] + ml[2][q] + ml[3][q];
        float inv = 1.0f / L;
        unsigned int packed[4];
        #pragma unroll
        for (int e2 = 0; e2 < 4; ++e2) {
            float Oa = o_l[0][d0 + 2 * e2][q] + o_l[1][d0 + 2 * e2][q]
                     + o_l[2][d0 + 2 * e2][q] + o_l[3][d0 + 2 * e2][q];
            float Ob = o_l[0][d0 + 2 * e2 + 1][q] + o_l[1][d0 + 2 * e2 + 1][q]
                     + o_l[2][d0 + 2 * e2 + 1][q] + o_l[3][d0 + 2 * e2 + 1][q];
            packed[e2] = (unsigned)f2bf(Oa * inv) | ((unsigned)f2bf(Ob * inv) << 16);
        }
        const int b = bh >> 4, hh = bh & 15;
        u32x4 pv; pv[0] = packed[0]; pv[1] = packed[1]; pv[2] = packed[2]; pv[3] = packed[3];
        *reinterpret_cast<u32x4*>(
            &ctx[((size_t)(b * SEQ + qw + q)) * HIDDEN + hh * HEAD_DIM + d0]) = pv;
    }
}

extern "C" void kernel_launch(void* const* d_in, const int* in_sizes, int n_in,
                              void* d_out, int out_size, void* d_ws, size_t ws_size,
                              hipStream_t stream) {
    const float* x        = (const float*)d_in[0];
    const float* residual = (const float*)d_in[1];
    const float* alibi    = (const float*)d_in[2];
    const float* W_qkv    = (const float*)d_in[4];
    const float* b_qkv    = (const float*)d_in[5];
    const float* W_dense  = (const float*)d_in[6];
    const float* b_dense  = (const float*)d_in[7];
    float* out = (float*)d_out;

    char* ws = (char*)d_ws;
    u16* xb  = (u16*)(ws);                 //  8 MB  x bf16
    u16* wqb = (u16*)(ws + 8388608);       //  6 MB  W_qkv bf16
    u16* wdb = (u16*)(ws + 14680064);      //  2 MB  W_dense bf16
    u16* q   = (u16*)(ws + 16777216);      //  8 MB  [B][H][S][64]
    u16* k   = (u16*)(ws + 25165824);      //  8 MB  [B][H][S][64]
    u16* vT  = (u16*)(ws + 33554432);      //  8 MB  [B][H][64][S]
    u16* ctx = (u16*)(ws + 41943040);      //  8 MB  [B*S][1024]
    float* kn = (float*)(ws + 50331648);   //  128 B per-bh max ||k||
    unsigned int* ctr = (unsigned int*)(ws + 50331648 + 256);

    cvt_all<<<8192, 256, 0, stream>>>(x, W_qkv, W_dense, xb, wqb, wdb);
    gemm_qkv<<<768, 256, 0, stream>>>(xb, wqb, b_qkv, q, k, vT);
    knorm_max<<<32, 256, 0, stream>>>(k, kn, ctr);
    attn<<<1024, 256, 0, stream>>>(q, k, vT, alibi, kn, ctx, ctr);
    gemm_dense<<<256, 256, 0, stream>>>(ctx, wdb, b_dense, residual, out);
}